// Round 6
// baseline (308.830 us; speedup 1.0000x reference)
//
#include <hip/hip_runtime.h>
#include <hip/hip_bf16.h>

#define AS1 __attribute__((address_space(1)))
#define AS3 __attribute__((address_space(3)))

typedef __bf16 bf16x8 __attribute__((ext_vector_type(8)));
typedef float f32x16 __attribute__((ext_vector_type(16)));

#define GLOAD_LDS16(gptr, lptr) \
  __builtin_amdgcn_global_load_lds((AS1 void*)(gptr), (AS3 void*)(lptr), 16, 0, 0)

#define M_W   4096   // output features (rows of W)
#define K_DIM 4096
#define M_X   8192   // batch*seq
#define NT_T  65536
#define TSTEPS 128
#define NKT   (K_DIM/64)   // 64 K-tiles of 64

#define BAR()        __builtin_amdgcn_s_barrier()
#define WAIT_LGKM0() asm volatile("s_waitcnt lgkmcnt(0)" ::: "memory")
#define VMW(n)       asm volatile("s_waitcnt vmcnt(" #n ")" ::: "memory")

__device__ __forceinline__ unsigned short f2bf(float f) {
  unsigned int u = __float_as_uint(f);
  unsigned int r = (u + 0x7FFFu + ((u >> 16) & 1u)) >> 16;
  return (unsigned short)r;
}

// ---------------- x fp32 -> bf16 ----------------
__global__ void cvt_kernel(const float* __restrict__ x, unsigned short* __restrict__ xb) {
  int idx = blockIdx.x * blockDim.x + threadIdx.x;
  const float4* p = reinterpret_cast<const float4*>(x) + (size_t)idx * 2;
  float4 u = p[0];
  float4 v = p[1];
  uint4 o;
  o.x = (unsigned)f2bf(u.x) | ((unsigned)f2bf(u.y) << 16);
  o.y = (unsigned)f2bf(u.z) | ((unsigned)f2bf(u.w) << 16);
  o.z = (unsigned)f2bf(v.x) | ((unsigned)f2bf(v.y) << 16);
  o.w = (unsigned)f2bf(v.z) | ((unsigned)f2bf(v.w) << 16);
  reinterpret_cast<uint4*>(xb)[idx] = o;
}

// ---------------- trellis decode -> W bf16 [4096][4096] ----------------
__global__ void decode_kernel(const int* __restrict__ trellis,
                              const float* __restrict__ tlut,
                              unsigned short* __restrict__ W) {
  int idx = blockIdx.x * blockDim.x + threadIdx.x;   // t*128 + s
  int t = idx >> 7;
  int s = idx & 127;
  const unsigned int* tr = reinterpret_cast<const unsigned int*>(trellis) + t * 32;
  int w0  = s >> 2;
  int off = (s & 3) * 4;
  unsigned int a = tr[w0] & 0xFFFFu;
  unsigned int state;
  if (off == 0) {
    state = a;
  } else {
    unsigned int b = tr[(w0 + 1) & 31] & 0xFFFFu;
    state = ((a << off) | (b >> (16 - off))) & 0xFFFFu;
  }
  unsigned int code = state & 0x1FFu;
  float2 v = reinterpret_cast<const float2*>(tlut)[code];
  int i = t >> 8;
  int j = t & 255;
  int flat = s * 2;
  int r = flat >> 4;
  int c = flat & 15;
  unsigned int packed = (unsigned)f2bf(v.x) | ((unsigned)f2bf(v.y) << 16);
  size_t o = (size_t)(i * 16 + r) * K_DIM + (j * 16 + c);
  *reinterpret_cast<unsigned int*>(W + o) = packed;
}

// ---------------- 256x256 8-phase bf16 GEMM, 32x32x16 MFMA ----------------
// LDS byte slots: A(buf,half) = (buf*2+half)*16384 ; B(buf,half) = 65536 + (buf*2+half)*16384
// Half-tile: 128 rows x 64 cols bf16, row stride 128B, 16B chunks XOR-swizzled (chunk ^= row&7).
// Phases per K-tile: (MH,KH) = (0,0),(0,1),(1,1),(1,0). Per phase: 8 MFMA 32x32x16,
// A reads 4 b128 (slot MH, 2 m-frags x 2 ks), B reads 4 b128 only in MH=0 phases (held in regs).

template<int BUF, int MH, int KH>
__device__ __forceinline__ void ldAq(const char* ldsc, int r0, int r1, const int* kc,
                                     bf16x8 av[2][2]) {
  const char* s = ldsc + (BUF * 2 + MH) * 16384;
  av[0][0] = *(const bf16x8*)(s + r0 + kc[2 * KH + 0]);
  av[0][1] = *(const bf16x8*)(s + r0 + kc[2 * KH + 1]);
  av[1][0] = *(const bf16x8*)(s + r1 + kc[2 * KH + 0]);
  av[1][1] = *(const bf16x8*)(s + r1 + kc[2 * KH + 1]);
}

template<int BUF, int KH>
__device__ __forceinline__ void ldBq(const char* ldsc, int br, const int* kc,
                                     bf16x8 bh[2][4]) {
  const char* s0 = ldsc + 65536 + (BUF * 2 + 0) * 16384;
  const char* s1 = ldsc + 65536 + (BUF * 2 + 1) * 16384;
  bh[0][2 * KH + 0] = *(const bf16x8*)(s0 + br + kc[2 * KH + 0]);
  bh[0][2 * KH + 1] = *(const bf16x8*)(s0 + br + kc[2 * KH + 1]);
  bh[1][2 * KH + 0] = *(const bf16x8*)(s1 + br + kc[2 * KH + 0]);
  bh[1][2 * KH + 1] = *(const bf16x8*)(s1 + br + kc[2 * KH + 1]);
}

template<int MH, int KH>
__device__ __forceinline__ void mm32(const bf16x8 av[2][2], const bf16x8 bh[2][4],
                                     f32x16 (&acc)[4][2]) {
  __builtin_amdgcn_s_setprio(1);
  #pragma unroll
  for (int kk = 0; kk < 2; ++kk)
    #pragma unroll
    for (int j = 0; j < 2; ++j)
      #pragma unroll
      for (int nf = 0; nf < 2; ++nf)
        acc[2 * MH + j][nf] =
            __builtin_amdgcn_mfma_f32_32x32x16_bf16(av[j][kk], bh[nf][2 * KH + kk],
                                                    acc[2 * MH + j][nf], 0, 0, 0);
  __builtin_amdgcn_s_setprio(0);
}

template<int BUF, int HALF>
__device__ __forceinline__ void stA(const unsigned short* xb, char* ldsc, int kt,
                                    int gArow0, int gArow1, int gcol, int lo0) {
  const unsigned short* s0 = xb + (size_t)(gArow0 + HALF * 64) * K_DIM + kt * 64 + gcol;
  const unsigned short* s1 = xb + (size_t)(gArow1 + HALF * 64) * K_DIM + kt * 64 + gcol;
  GLOAD_LDS16(s0, ldsc + (BUF * 2 + HALF) * 16384 + lo0);
  GLOAD_LDS16(s1, ldsc + (BUF * 2 + HALF) * 16384 + lo0 + 1024);
}

template<int BUF, int HALF>
__device__ __forceinline__ void stB(const unsigned short* W, char* ldsc, int kt,
                                    int gBrow0, int gBrow1, int gcol, int lo0) {
  const unsigned short* s0 = W + (size_t)(gBrow0 + HALF * 32) * K_DIM + kt * 64 + gcol;
  const unsigned short* s1 = W + (size_t)(gBrow1 + HALF * 32) * K_DIM + kt * 64 + gcol;
  GLOAD_LDS16(s0, ldsc + 65536 + (BUF * 2 + HALF) * 16384 + lo0);
  GLOAD_LDS16(s1, ldsc + 65536 + (BUF * 2 + HALF) * 16384 + lo0 + 1024);
}

__global__ __launch_bounds__(512, 2) void gemm8_kernel(const unsigned short* __restrict__ xb,
                                                       const unsigned short* __restrict__ W,
                                                       float* __restrict__ y) {
  extern __shared__ __align__(16) char ldsc[];   // 131072 bytes

  // XCD-aware bijective swizzle: 512 blocks, 8 XCDs, 64 per XCD
  int bid = blockIdx.x;
  int swz = (bid & 7) * 64 + (bid >> 3);
  int brow = (swz >> 4) * 256;   // 32 row-tiles
  int bcol = (swz & 15) * 256;   // 16 col-tiles

  int tid  = threadIdx.x;
  int lane = tid & 63;
  int wid  = tid >> 6;
  int wr = wid >> 2;     // 0..1
  int wc = wid & 3;      // 0..3

  // ds_read addressing for 32x32x16 frags: row = lane&31, k-elems (lane>>5)*8 per ks
  int l31 = lane & 31, la7 = lane & 7, hi = lane >> 5;
  int kc[4];
  #pragma unroll
  for (int ks = 0; ks < 4; ++ks) kc[ks] = ((2 * ks + hi) ^ la7) << 4;
  int aR0 = (wr * 64 + 0 * 32 + l31) * 128;   // m-frag 2*MH+0 (slot-local)
  int aR1 = (wr * 64 + 1 * 32 + l31) * 128;   // m-frag 2*MH+1
  int bR  = (wc * 32 + l31) * 128;            // n-frag = slot index

  // staging addressing (unchanged)
  int q0 = wid * 16 + (lane >> 3);
  int q1 = q0 + 8;
  int lo0 = wid * 2048 + lane * 16;
  int gcol = ((lane & 7) ^ (lane >> 3)) << 3;   // pre-swizzled source chunk
  int gArow0 = brow + (q0 >> 6) * 128 + (q0 & 63);
  int gArow1 = brow + (q1 >> 6) * 128 + (q1 & 63);
  int gBrow0 = bcol + (q0 >> 5) * 64 + (q0 & 31);
  int gBrow1 = bcol + (q1 >> 5) * 64 + (q1 & 31);

  f32x16 acc[4][2];
  #pragma unroll
  for (int m = 0; m < 4; ++m)
    #pragma unroll
    for (int n = 0; n < 2; ++n)
      #pragma unroll
      for (int e = 0; e < 16; ++e)
        acc[m][n][e] = 0.f;

  bf16x8 av[2][2];    // A frags for current phase
  bf16x8 bh[2][4];    // B frags for current K-tile (held across M-halves)

  // prologue: buf0 <- t0 (A0,A1,B0,B1), buf1 <- t1 (A0,B0,B1); buf1.A1 staged in ph1
  stA<0,0>(xb, ldsc, 0, gArow0, gArow1, gcol, lo0);
  stA<0,1>(xb, ldsc, 0, gArow0, gArow1, gcol, lo0);
  stB<0,0>(W,  ldsc, 0, gBrow0, gBrow1, gcol, lo0);
  stB<0,1>(W,  ldsc, 0, gBrow0, gBrow1, gcol, lo0);
  stA<1,0>(xb, ldsc, 1, gArow0, gArow1, gcol, lo0);
  stB<1,0>(W,  ldsc, 1, gBrow0, gBrow1, gcol, lo0);
  stB<1,1>(W,  ldsc, 1, gBrow0, gBrow1, gcol, lo0);
  VMW(0); BAR();

  // stage calendar (per iter): ph1: b1A1<-t1 | ph2: - | ph3: b0A0,b0B0<-t2 | ph4: b0B1<-t2
  //                            ph5: b0A1<-t2 | ph6: - | ph7: b1A0,b1B0<-t3 | ph8: b1B1<-t3
  // issue counts [2,0,4,2,2,0,4,2]; end-of-phase gates [10,8,12,8,10,8,12,8] (margin>=5 ph)
  #pragma unroll 1
  for (int i = 0; i < NKT / 2; ++i) {
    int t1 = 2 * i + 1;
    int t2 = 2 * i + 2; if (t2 > NKT - 1) t2 = NKT - 1;
    int t3 = 2 * i + 3; if (t3 > NKT - 1) t3 = NKT - 1;

    // ph1: buf0 (MH0,KH0); stage buf1.A1 <- t1
    ldAq<0,0,0>(ldsc, aR0, aR1, kc, av);
    ldBq<0,0>(ldsc, bR, kc, bh);
    stA<1,1>(xb, ldsc, t1, gArow0, gArow1, gcol, lo0);
    BAR(); WAIT_LGKM0();
    mm32<0,0>(av, bh, acc);
    VMW(10); BAR();

    // ph2: (MH0,KH1)
    ldAq<0,0,1>(ldsc, aR0, aR1, kc, av);
    ldBq<0,1>(ldsc, bR, kc, bh);
    BAR(); WAIT_LGKM0();
    mm32<0,1>(av, bh, acc);
    VMW(8); BAR();

    // ph3: (MH1,KH1); stage buf0.A0, buf0.B0 <- t2
    ldAq<0,1,1>(ldsc, aR0, aR1, kc, av);
    stA<0,0>(xb, ldsc, t2, gArow0, gArow1, gcol, lo0);
    stB<0,0>(W,  ldsc, t2, gBrow0, gBrow1, gcol, lo0);
    BAR(); WAIT_LGKM0();
    mm32<1,1>(av, bh, acc);
    VMW(12); BAR();

    // ph4: (MH1,KH0); stage buf0.B1 <- t2
    ldAq<0,1,0>(ldsc, aR0, aR1, kc, av);
    stB<0,1>(W, ldsc, t2, gBrow0, gBrow1, gcol, lo0);
    BAR(); WAIT_LGKM0();
    mm32<1,0>(av, bh, acc);
    VMW(8); BAR();

    // ph5: buf1 (MH0,KH0); stage buf0.A1 <- t2
    ldAq<1,0,0>(ldsc, aR0, aR1, kc, av);
    ldBq<1,0>(ldsc, bR, kc, bh);
    stA<0,1>(xb, ldsc, t2, gArow0, gArow1, gcol, lo0);
    BAR(); WAIT_LGKM0();
    mm32<0,0>(av, bh, acc);
    VMW(10); BAR();

    // ph6: (MH0,KH1)
    ldAq<1,0,1>(ldsc, aR0, aR1, kc, av);
    ldBq<1,1>(ldsc, bR, kc, bh);
    BAR(); WAIT_LGKM0();
    mm32<0,1>(av, bh, acc);
    VMW(8); BAR();

    // ph7: (MH1,KH1); stage buf1.A0, buf1.B0 <- t3
    ldAq<1,1,1>(ldsc, aR0, aR1, kc, av);
    stA<1,0>(xb, ldsc, t3, gArow0, gArow1, gcol, lo0);
    stB<1,0>(W,  ldsc, t3, gBrow0, gBrow1, gcol, lo0);
    BAR(); WAIT_LGKM0();
    mm32<1,1>(av, bh, acc);
    VMW(12); BAR();

    // ph8: (MH1,KH0); stage buf1.B1 <- t3
    ldAq<1,1,0>(ldsc, aR0, aR1, kc, av);
    stB<1,1>(W, ldsc, t3, gBrow0, gBrow1, gcol, lo0);
    BAR(); WAIT_LGKM0();
    mm32<1,0>(av, bh, acc);
    VMW(8); BAR();
  }

  VMW(0);

  // epilogue: 32x32 C/D layout col=lane&31, row=(reg&3)+8*(reg>>2)+4*(lane>>5)
  #pragma unroll
  for (int mf = 0; mf < 4; ++mf) {
    #pragma unroll
    for (int nf = 0; nf < 2; ++nf) {
      int col = bcol + wc * 64 + nf * 32 + l31;
      int rb  = brow + wr * 128 + mf * 32 + 4 * hi;
      #pragma unroll
      for (int g = 0; g < 4; ++g) {
        #pragma unroll
        for (int e = 0; e < 4; ++e) {
          y[(size_t)(rb + g * 8 + e) * M_W + col] = acc[mf][nf][g * 4 + e];
        }
      }
    }
  }
}

extern "C" void kernel_launch(void* const* d_in, const int* in_sizes, int n_in,
                              void* d_out, int out_size, void* d_ws, size_t ws_size,
                              hipStream_t stream) {
  const float* inp     = (const float*)d_in[0];
  const int*   trellis = (const int*)d_in[1];
  const float* tlut    = (const float*)d_in[2];
  float* y = (float*)d_out;

  unsigned short* xb = (unsigned short*)d_ws;                                      // 64 MiB
  unsigned short* Wd = (unsigned short*)((char*)d_ws + (size_t)M_X * K_DIM * 2);   // 32 MiB

  (void)hipFuncSetAttribute((const void*)gemm8_kernel,
                            hipFuncAttributeMaxDynamicSharedMemorySize, 131072);

  cvt_kernel<<<M_X * K_DIM / 8 / 256, 256, 0, stream>>>(inp, xb);
  decode_kernel<<<NT_T * TSTEPS / 256, 256, 0, stream>>>(trellis, tlut, Wd);
  gemm8_kernel<<<dim3(512), dim3(512), 131072, stream>>>(xb, Wd, y);
}

// Round 7
// 272.663 us; speedup vs baseline: 1.1326x; 1.1326x over previous
//
#include <hip/hip_runtime.h>
#include <hip/hip_bf16.h>

#define AS1 __attribute__((address_space(1)))
#define AS3 __attribute__((address_space(3)))

typedef __bf16 bf16x8 __attribute__((ext_vector_type(8)));
typedef float f32x4 __attribute__((ext_vector_type(4)));

#define GLOAD_LDS16(gptr, lptr) \
  __builtin_amdgcn_global_load_lds((AS1 void*)(gptr), (AS3 void*)(lptr), 16, 0, 0)

#define M_W   4096   // output features (rows of W)
#define K_DIM 4096
#define M_X   8192   // batch*seq
#define NT_T  65536
#define NKT   (K_DIM/64)   // 64 K-tiles of 64
#define CVT_BLOCKS 16384   // M_X*K_DIM/8/256

#define BAR()        __builtin_amdgcn_s_barrier()
#define WAIT_LGKM0() asm volatile("s_waitcnt lgkmcnt(0)" ::: "memory")
#define WAIT_LGKM8() asm volatile("s_waitcnt lgkmcnt(8)" ::: "memory")
#define WAIT_VM10()  asm volatile("s_waitcnt vmcnt(10)" ::: "memory")
#define WAIT_VM0()   asm volatile("s_waitcnt vmcnt(0)" ::: "memory")

__device__ __forceinline__ unsigned short f2bf(float f) {
  unsigned int u = __float_as_uint(f);
  unsigned int r = (u + 0x7FFFu + ((u >> 16) & 1u)) >> 16;
  return (unsigned short)r;
}

// ---------------- fused prep: x fp32->bf16 (1/3 of blocks) + trellis decode (2/3) ----------------
__global__ void prep_kernel(const float* __restrict__ x,
                            const int* __restrict__ trellis,
                            const float* __restrict__ tlut,
                            unsigned short* __restrict__ xb,
                            unsigned short* __restrict__ W) {
  int b = blockIdx.x;
  int tid = threadIdx.x;
  if (b % 3 == 0) {
    // cvt path: block handles 256 threads x 8 elems
    int idx = (b / 3) * 256 + tid;
    const float4* p = reinterpret_cast<const float4*>(x) + (size_t)idx * 2;
    float4 u = p[0];
    float4 v = p[1];
    uint4 o;
    o.x = (unsigned)f2bf(u.x) | ((unsigned)f2bf(u.y) << 16);
    o.y = (unsigned)f2bf(u.z) | ((unsigned)f2bf(u.w) << 16);
    o.z = (unsigned)f2bf(v.x) | ((unsigned)f2bf(v.y) << 16);
    o.w = (unsigned)f2bf(v.z) | ((unsigned)f2bf(v.w) << 16);
    reinterpret_cast<uint4*>(xb)[idx] = o;
  } else {
    // decode path
    int db = b - b / 3 - 1;                     // 0..32767
    int idx = db * 256 + tid;                   // t*128 + s
    int t = idx >> 7;
    int s = idx & 127;
    const unsigned int* tr = reinterpret_cast<const unsigned int*>(trellis) + t * 32;
    int w0  = s >> 2;
    int off = (s & 3) * 4;
    unsigned int a = tr[w0] & 0xFFFFu;
    unsigned int state;
    if (off == 0) {
      state = a;
    } else {
      unsigned int bb = tr[(w0 + 1) & 31] & 0xFFFFu;
      state = ((a << off) | (bb >> (16 - off))) & 0xFFFFu;
    }
    unsigned int code = state & 0x1FFu;
    float2 v = reinterpret_cast<const float2*>(tlut)[code];
    int i = t >> 8;
    int j = t & 255;
    int flat = s * 2;
    int r = flat >> 4;
    int c = flat & 15;
    unsigned int packed = (unsigned)f2bf(v.x) | ((unsigned)f2bf(v.y) << 16);
    size_t o = (size_t)(i * 16 + r) * K_DIM + (j * 16 + c);
    *reinterpret_cast<unsigned int*>(W + o) = packed;
  }
}

// ---------------- 256x256 8-phase bf16 GEMM (R3 schedule + pointer-precompute) ----------------
// y[8192,4096] = xb[8192,4096] * W[4096,4096]^T
// LDS byte slots: A(buf,half) = (buf*2+half)*16384 ; B(buf,half) = 65536 + (buf*2+half)*16384
// Half-tile: 128 rows x 64 cols bf16, row stride 128B, 16B chunks XOR-swizzled (chunk ^= row&7).
// Stage calendar: every slot staged >=6 phases before first read; per-phase vmcnt(10) gate.

template<int BUF, int MH>
__device__ __forceinline__ void lda(const char* ldsc, const int* aRow, const int* kOff,
                                    bf16x8 af[4][2]) {
  const char* base = ldsc + (BUF * 2 + MH) * 16384;
  #pragma unroll
  for (int fm = 0; fm < 4; ++fm)
    #pragma unroll
    for (int kh = 0; kh < 2; ++kh)
      af[fm][kh] = *(const bf16x8*)(base + aRow[fm] + kOff[kh]);
}

template<int BUF, int NH>
__device__ __forceinline__ void ldb(const char* ldsc, const int* bRow, const int* kOff,
                                    bf16x8 bq[2][2]) {
  const char* base = ldsc + 65536 + (BUF * 2 + NH) * 16384;
  #pragma unroll
  for (int fn = 0; fn < 2; ++fn)
    #pragma unroll
    for (int kh = 0; kh < 2; ++kh)
      bq[fn][kh] = *(const bf16x8*)(base + bRow[fn] + kOff[kh]);
}

template<int MH, int NH>
__device__ __forceinline__ void mm(bf16x8 af[4][2], bf16x8 bq[2][2], f32x4 acc[8][4]) {
  __builtin_amdgcn_s_setprio(1);
  #pragma unroll
  for (int fm = 0; fm < 4; ++fm)
    #pragma unroll
    for (int fn = 0; fn < 2; ++fn)
      #pragma unroll
      for (int kh = 0; kh < 2; ++kh)
        acc[MH * 4 + fm][NH * 2 + fn] =
            __builtin_amdgcn_mfma_f32_16x16x32_bf16(af[fm][kh], bq[fn][kh],
                                                    acc[MH * 4 + fm][NH * 2 + fn], 0, 0, 0);
  __builtin_amdgcn_s_setprio(0);
}

// stage one half-tile slot: two precomputed source pointers + k-offset, LDS dst slot
__device__ __forceinline__ void stage2(const unsigned short* s0, const unsigned short* s1,
                                       int ko, char* dst) {
  GLOAD_LDS16(s0 + ko, dst);
  GLOAD_LDS16(s1 + ko, dst + 1024);
}

__global__ __launch_bounds__(512) void gemm8_kernel(const unsigned short* __restrict__ xb,
                                                    const unsigned short* __restrict__ W,
                                                    float* __restrict__ y) {
  extern __shared__ __align__(16) char ldsc[];   // 131072 bytes

  // XCD-aware bijective swizzle: 512 blocks, 8 XCDs, 64 per XCD
  int bid = blockIdx.x;
  int swz = (bid & 7) * 64 + (bid >> 3);
  int brow = (swz >> 4) * 256;   // 32 row-tiles
  int bcol = (swz & 15) * 256;   // 16 col-tiles

  int tid  = threadIdx.x;
  int lane = tid & 63;
  int wid  = tid >> 6;
  int wr = wid >> 2;     // 0..1
  int wc = wid & 3;      // 0..3

  // ds_read addressing (within a 16 KiB half-slot)
  int kOff[2], aRow[4], bRow[2];
  #pragma unroll
  for (int kh = 0; kh < 2; ++kh) kOff[kh] = ((kh * 4 + (lane >> 4)) ^ (lane & 7)) << 4;
  #pragma unroll
  for (int fm = 0; fm < 4; ++fm) aRow[fm] = (wr * 64 + fm * 16 + (lane & 15)) << 7;
  #pragma unroll
  for (int fn = 0; fn < 2; ++fn) bRow[fn] = (wc * 32 + fn * 16 + (lane & 15)) << 7;

  // staging addressing: precompute 8 global base pointers (row*K folded once)
  int q0 = wid * 16 + (lane >> 3);
  int q1 = q0 + 8;
  int lo0 = wid * 2048 + lane * 16;
  int gcol = ((lane & 7) ^ (lane >> 3)) << 3;   // pre-swizzled source chunk
  int gArow0 = brow + (q0 >> 6) * 128 + (q0 & 63);
  int gArow1 = brow + (q1 >> 6) * 128 + (q1 & 63);
  int gBrow0 = bcol + (q0 >> 5) * 64 + (q0 & 31);
  int gBrow1 = bcol + (q1 >> 5) * 64 + (q1 & 31);

  const unsigned short* pA_h0_0 = xb + (size_t)gArow0 * K_DIM + gcol;
  const unsigned short* pA_h0_1 = xb + (size_t)gArow1 * K_DIM + gcol;
  const unsigned short* pA_h1_0 = xb + (size_t)(gArow0 + 64) * K_DIM + gcol;
  const unsigned short* pA_h1_1 = xb + (size_t)(gArow1 + 64) * K_DIM + gcol;
  const unsigned short* pB_h0_0 = W + (size_t)gBrow0 * K_DIM + gcol;
  const unsigned short* pB_h0_1 = W + (size_t)gBrow1 * K_DIM + gcol;
  const unsigned short* pB_h1_0 = W + (size_t)(gBrow0 + 32) * K_DIM + gcol;
  const unsigned short* pB_h1_1 = W + (size_t)(gBrow1 + 32) * K_DIM + gcol;

  // LDS dst slot bases (per-thread, +lo0 folded)
  char* dA00 = ldsc + 0 * 16384 + lo0;
  char* dA01 = ldsc + 1 * 16384 + lo0;
  char* dA10 = ldsc + 2 * 16384 + lo0;
  char* dA11 = ldsc + 3 * 16384 + lo0;
  char* dB00 = ldsc + 65536 + 0 * 16384 + lo0;
  char* dB01 = ldsc + 65536 + 1 * 16384 + lo0;
  char* dB10 = ldsc + 65536 + 2 * 16384 + lo0;
  char* dB11 = ldsc + 65536 + 3 * 16384 + lo0;

  f32x4 acc[8][4];
  #pragma unroll
  for (int m = 0; m < 8; ++m)
    #pragma unroll
    for (int n = 0; n < 4; ++n)
      acc[m][n] = (f32x4){0.f, 0.f, 0.f, 0.f};

  bf16x8 af[4][2];
  bf16x8 bq[2][2][2];    // [NH][fn][kh]

  // prologue: buf0 <- t0 (all four), buf1 <- t1 (A0,B0,B1); buf1-A1 staged in ph1
  stage2(pA_h0_0, pA_h0_1, 0,  dA00);
  stage2(pB_h0_0, pB_h0_1, 0,  dB00);
  stage2(pB_h1_0, pB_h1_1, 0,  dB01);
  stage2(pA_h1_0, pA_h1_1, 0,  dA01);
  stage2(pA_h0_0, pA_h0_1, 64, dA10);
  stage2(pB_h0_0, pB_h0_1, 64, dB10);
  stage2(pB_h1_0, pB_h1_1, 64, dB11);
  WAIT_VM0(); BAR();

  #pragma unroll 1
  for (int i = 0; i < NKT / 2; ++i) {
    int k1 = (2 * i + 1) * 64;
    int t2 = 2 * i + 2; if (t2 > NKT - 1) t2 = NKT - 1;
    int t3 = 2 * i + 3; if (t3 > NKT - 1) t3 = NKT - 1;
    int k2 = t2 * 64;
    int k3 = t3 * 64;

    // ph1: quadrant (0,0) of buf0; stage buf1-A1 <- t1 (read ph7, 6 phases)
    lda<0,0>(ldsc, aRow, kOff, af);
    ldb<0,0>(ldsc, bRow, kOff, bq[0]);
    stage2(pA_h1_0, pA_h1_1, k1, dA11);
    WAIT_LGKM8(); BAR(); WAIT_LGKM0();
    mm<0,0>(af, bq[0], acc);
    WAIT_VM10(); BAR();
    // ph2: (0,1); stage buf0-A0 <- t2 (read next ph1, 7 phases)
    ldb<0,1>(ldsc, bRow, kOff, bq[1]);
    stage2(pA_h0_0, pA_h0_1, k2, dA00);
    BAR(); WAIT_LGKM0();
    mm<0,1>(af, bq[1], acc);
    WAIT_VM10(); BAR();
    // ph3: (1,1); stage buf0-B0 <- t2 (read next ph1, 6 phases)
    lda<0,1>(ldsc, aRow, kOff, af);
    stage2(pB_h0_0, pB_h0_1, k2, dB00);
    BAR(); WAIT_LGKM0();
    mm<1,1>(af, bq[1], acc);
    WAIT_VM10(); BAR();
    // ph4: (1,0) — B in regs; stage buf0-B1 <- t2 (read next ph2, 6 phases)
    stage2(pB_h1_0, pB_h1_1, k2, dB01);
    BAR();
    mm<1,0>(af, bq[0], acc);
    WAIT_VM10(); BAR();
    // ph5: quadrant (0,0) of buf1; stage buf0-A1 <- t2 (read next ph3, 6 phases)
    lda<1,0>(ldsc, aRow, kOff, af);
    ldb<1,0>(ldsc, bRow, kOff, bq[0]);
    stage2(pA_h1_0, pA_h1_1, k2, dA01);
    WAIT_LGKM8(); BAR(); WAIT_LGKM0();
    mm<0,0>(af, bq[0], acc);
    WAIT_VM10(); BAR();
    // ph6: (0,1); stage buf1-A0 <- t3 (read next ph5, 7 phases)
    ldb<1,1>(ldsc, bRow, kOff, bq[1]);
    stage2(pA_h0_0, pA_h0_1, k3, dA10);
    BAR(); WAIT_LGKM0();
    mm<0,1>(af, bq[1], acc);
    WAIT_VM10(); BAR();
    // ph7: (1,1); stage buf1-B0 <- t3 (read next ph5, 6 phases)
    lda<1,1>(ldsc, aRow, kOff, af);
    stage2(pB_h0_0, pB_h0_1, k3, dB10);
    BAR(); WAIT_LGKM0();
    mm<1,1>(af, bq[1], acc);
    WAIT_VM10(); BAR();
    // ph8: (1,0) — B in regs; stage buf1-B1 <- t3 (read next ph6, 6 phases)
    stage2(pB_h1_0, pB_h1_1, k3, dB11);
    BAR();
    mm<1,0>(af, bq[0], acc);
    WAIT_VM10(); BAR();
  }

  WAIT_VM0(); BAR();

  // epilogue: C/D layout col=lane&15, row=(lane>>4)*4+j
  #pragma unroll
  for (int am = 0; am < 8; ++am) {
    #pragma unroll
    for (int an = 0; an < 4; ++an) {
      int row0 = brow + wr * 128 + am * 16 + (lane >> 4) * 4;
      int col  = bcol + wc * 64 + an * 16 + (lane & 15);
      #pragma unroll
      for (int j = 0; j < 4; ++j)
        y[(size_t)(row0 + j) * M_W + col] = acc[am][an][j];
    }
  }
}

extern "C" void kernel_launch(void* const* d_in, const int* in_sizes, int n_in,
                              void* d_out, int out_size, void* d_ws, size_t ws_size,
                              hipStream_t stream) {
  const float* inp     = (const float*)d_in[0];
  const int*   trellis = (const int*)d_in[1];
  const float* tlut    = (const float*)d_in[2];
  float* y = (float*)d_out;

  unsigned short* xb = (unsigned short*)d_ws;                                      // 64 MiB
  unsigned short* Wd = (unsigned short*)((char*)d_ws + (size_t)M_X * K_DIM * 2);   // 32 MiB

  (void)hipFuncSetAttribute((const void*)gemm8_kernel,
                            hipFuncAttributeMaxDynamicSharedMemorySize, 131072);

  prep_kernel<<<49152, 256, 0, stream>>>(inp, trellis, tlut, xb, Wd);
  gemm8_kernel<<<dim3(512), dim3(512), 131072, stream>>>(xb, Wd, y);
}